// Round 1
// baseline (300.671 us; speedup 1.0000x reference)
//
#include <hip/hip_runtime.h>
#include <hip/hip_bf16.h>

// Problem constants
#define LSEQ 32768
#define HDIM 256
#define PDIM 256
#define CHUNK 64
#define NCHUNK (LSEQ / CHUNK)   // 512

// ---------------------------------------------------------------------------
// prep1: per-channel discretization + power table Abar^k, k=0..CHUNK
// ---------------------------------------------------------------------------
__global__ void s5_prep1(const float* __restrict__ Lambda,
                         const float* __restrict__ log_step,
                         float* __restrict__ Abar,   // (P,2)
                         float* __restrict__ g,      // (P,2)  BL*step
                         float* __restrict__ powt)   // (CHUNK+1, 2P)
{
    int p = threadIdx.x;
    float lr = Lambda[2 * p], li = Lambda[2 * p + 1];
    float step = expf(log_step[p]);          // STEP_SCALE = 1
    float s2 = 0.5f * step;
    // BL = 1 / (1 - s2*lam)
    float dr = 1.0f - s2 * lr;
    float di = -s2 * li;
    float inv = 1.0f / (dr * dr + di * di);
    float blr = dr * inv, bli = -di * inv;
    // Lambda_bar = BL * (1 + s2*lam)
    float nr = 1.0f + s2 * lr, ni = s2 * li;
    float ar = blr * nr - bli * ni;
    float ai = blr * ni + bli * nr;
    Abar[2 * p] = ar; Abar[2 * p + 1] = ai;
    g[2 * p] = blr * step; g[2 * p + 1] = bli * step;

    float pr = 1.0f, pi = 0.0f;
    powt[0 * 512 + 2 * p] = 1.0f; powt[0 * 512 + 2 * p + 1] = 0.0f;
    for (int k = 1; k <= CHUNK; ++k) {
        float t = pr * ar - pi * ai;
        pi = pr * ai + pi * ar;
        pr = t;
        powt[k * 512 + 2 * p] = pr;
        powt[k * 512 + 2 * p + 1] = pi;
    }
}

// ---------------------------------------------------------------------------
// prep2: build GEMM weight matrices
//   W1 (H x 2P): W1[h][2p] = Re(g_p * B[p][h]), W1[h][2p+1] = Im(...)
//   W2 (2P x H): W2[2p][h] = C_re[h][p], W2[2p+1][h] = -C_im[h][p]
// ---------------------------------------------------------------------------
__global__ void s5_prep2(const float* __restrict__ B,
                         const float* __restrict__ C,
                         const float* __restrict__ g,
                         float* __restrict__ W1,
                         float* __restrict__ W2)
{
    int b = blockIdx.x, t = threadIdx.x;
    {   // W1: h = b, p = t
        int h = b, p = t;
        float gr = g[2 * p], gi = g[2 * p + 1];
        float br = B[(size_t)(p * HDIM + h) * 2];
        float bi = B[(size_t)(p * HDIM + h) * 2 + 1];
        W1[(size_t)h * 512 + 2 * p]     = gr * br - gi * bi;
        W1[(size_t)h * 512 + 2 * p + 1] = gr * bi + gi * br;
    }
    {   // W2: p = b, h = t
        int p = b, h = t;
        float cr = C[(size_t)(h * PDIM + p) * 2];
        float ci = C[(size_t)(h * PDIM + p) * 2 + 1];
        W2[(size_t)(2 * p) * HDIM + h]     = cr;
        W2[(size_t)(2 * p + 1) * HDIM + h] = -ci;
    }
}

// ---------------------------------------------------------------------------
// GEMM1: Bu (L x 512) = u (L x 256) @ W1 (256 x 512)
// 64x64 tile, BK=32, 256 threads, 4x4 micro-tile
// ---------------------------------------------------------------------------
__global__ __launch_bounds__(256) void s5_gemm1(const float* __restrict__ A,
                                                const float* __restrict__ W,
                                                float* __restrict__ Out)
{
    __shared__ float As[32][68];   // transposed: As[k][m], pad 64->68 keeps 16B align
    __shared__ float Bs[32][64];
    const int tid = threadIdx.x;
    const int tx = tid & 15, ty = tid >> 4;
    const int n0 = blockIdx.x * 64;
    const int m0 = blockIdx.y * 64;
    float acc[4][4] = {};

    for (int k0 = 0; k0 < 256; k0 += 32) {
        #pragma unroll
        for (int i = 0; i < 2; ++i) {
            int lin = tid + i * 256;
            int r = lin >> 3, c4 = (lin & 7) << 2;
            float4 v = *(const float4*)&A[(size_t)(m0 + r) * 256 + k0 + c4];
            As[c4 + 0][r] = v.x; As[c4 + 1][r] = v.y;
            As[c4 + 2][r] = v.z; As[c4 + 3][r] = v.w;
        }
        #pragma unroll
        for (int i = 0; i < 2; ++i) {
            int lin = tid + i * 256;
            int r = lin >> 4, c4 = (lin & 15) << 2;
            *(float4*)&Bs[r][c4] = *(const float4*)&W[(size_t)(k0 + r) * 512 + n0 + c4];
        }
        __syncthreads();
        #pragma unroll
        for (int k = 0; k < 32; ++k) {
            float4 a = *(const float4*)&As[k][ty << 2];
            float4 b = *(const float4*)&Bs[k][tx << 2];
            float av[4] = {a.x, a.y, a.z, a.w};
            float bv[4] = {b.x, b.y, b.z, b.w};
            #pragma unroll
            for (int ii = 0; ii < 4; ++ii)
                #pragma unroll
                for (int jj = 0; jj < 4; ++jj)
                    acc[ii][jj] = fmaf(av[ii], bv[jj], acc[ii][jj]);
        }
        __syncthreads();
    }
    #pragma unroll
    for (int ii = 0; ii < 4; ++ii) {
        float4 o = make_float4(acc[ii][0], acc[ii][1], acc[ii][2], acc[ii][3]);
        *(float4*)&Out[(size_t)(m0 + (ty << 2) + ii) * 512 + n0 + (tx << 2)] = o;
    }
}

// ---------------------------------------------------------------------------
// scan1: per-chunk local scan, in place on Bu. grid=(NCHUNK), block=(P)
// ---------------------------------------------------------------------------
__global__ void s5_scan1(float* xs,                       // (L, 2P) in/out
                         const float* __restrict__ Abar,  // (P,2)
                         float* __restrict__ local_end)   // (NCHUNK, 2P)
{
    int p = threadIdx.x;
    int c = blockIdx.x;
    float2 a = ((const float2*)Abar)[p];
    float xr = 0.0f, xi = 0.0f;
    const size_t base = (size_t)c * CHUNK;
    float2* xsv = (float2*)xs;
    for (int t = 0; t < CHUNK; ++t) {
        float2 bu = xsv[(base + t) * 256 + p];
        float nr = fmaf(a.x, xr, fmaf(-a.y, xi, bu.x));
        float ni = fmaf(a.x, xi, fmaf(a.y, xr, bu.y));
        xr = nr; xi = ni;
        xsv[(base + t) * 256 + p] = make_float2(xr, xi);
    }
    ((float2*)local_end)[(size_t)c * 256 + p] = make_float2(xr, xi);
}

// ---------------------------------------------------------------------------
// scan2: sequential scan over chunk carries (one block), emits carry_in per
// chunk and the final state into d_out tail.
// ---------------------------------------------------------------------------
__global__ void s5_scan2(const float* __restrict__ local_end, // (NCHUNK, 2P)
                         float* __restrict__ carry_in,        // (NCHUNK, 2P)
                         const float* __restrict__ powt,      // (CHUNK+1, 2P)
                         float* __restrict__ out_state)       // (P,2)
{
    int p = threadIdx.x;
    float2 A = ((const float2*)powt)[CHUNK * 256 + p];  // Abar^CHUNK
    float cr = 0.0f, ci = 0.0f;
    for (int c = 0; c < NCHUNK; ++c) {
        ((float2*)carry_in)[(size_t)c * 256 + p] = make_float2(cr, ci);
        float2 e = ((const float2*)local_end)[(size_t)c * 256 + p];
        float nr = fmaf(A.x, cr, fmaf(-A.y, ci, e.x));
        float ni = fmaf(A.x, ci, fmaf(A.y, cr, e.y));
        cr = nr; ci = ni;
    }
    out_state[2 * p] = cr;
    out_state[2 * p + 1] = ci;
}

// ---------------------------------------------------------------------------
// GEMM2: ys (L x 256) = fixup(xs) (L x 512) @ W2 (512 x 256) + D*u
// fixup applied during A-tile load: xs += Abar^{(l%CHUNK)+1} * carry[l/CHUNK]
// ---------------------------------------------------------------------------
__global__ __launch_bounds__(256) void s5_gemm2(const float* __restrict__ XS,
                                                const float* __restrict__ W,
                                                const float* __restrict__ carry,
                                                const float* __restrict__ powt,
                                                const float* __restrict__ Dv,
                                                const float* __restrict__ U,
                                                float* __restrict__ Out)
{
    __shared__ float As[32][68];
    __shared__ float Bs[32][64];
    const int tid = threadIdx.x;
    const int tx = tid & 15, ty = tid >> 4;
    const int n0 = blockIdx.x * 64;
    const int m0 = blockIdx.y * 64;
    const int chunk = m0 >> 6;   // CHUNK == tile M == 64, aligned
    float acc[4][4] = {};

    for (int k0 = 0; k0 < 512; k0 += 32) {
        #pragma unroll
        for (int i = 0; i < 2; ++i) {
            int lin = tid + i * 256;
            int r = lin >> 3, c4 = (lin & 7) << 2;
            int row = m0 + r;
            float4 v  = *(const float4*)&XS[(size_t)row * 512 + k0 + c4];
            int kp = (row & (CHUNK - 1)) + 1;
            float4 pw = *(const float4*)&powt[(size_t)kp * 512 + k0 + c4];
            float4 cv = *(const float4*)&carry[(size_t)chunk * 512 + k0 + c4];
            v.x += pw.x * cv.x - pw.y * cv.y;
            v.y += pw.x * cv.y + pw.y * cv.x;
            v.z += pw.z * cv.z - pw.w * cv.w;
            v.w += pw.z * cv.w + pw.w * cv.z;
            As[c4 + 0][r] = v.x; As[c4 + 1][r] = v.y;
            As[c4 + 2][r] = v.z; As[c4 + 3][r] = v.w;
        }
        #pragma unroll
        for (int i = 0; i < 2; ++i) {
            int lin = tid + i * 256;
            int r = lin >> 4, c4 = (lin & 15) << 2;
            *(float4*)&Bs[r][c4] = *(const float4*)&W[(size_t)(k0 + r) * 256 + n0 + c4];
        }
        __syncthreads();
        #pragma unroll
        for (int k = 0; k < 32; ++k) {
            float4 a = *(const float4*)&As[k][ty << 2];
            float4 b = *(const float4*)&Bs[k][tx << 2];
            float av[4] = {a.x, a.y, a.z, a.w};
            float bv[4] = {b.x, b.y, b.z, b.w};
            #pragma unroll
            for (int ii = 0; ii < 4; ++ii)
                #pragma unroll
                for (int jj = 0; jj < 4; ++jj)
                    acc[ii][jj] = fmaf(av[ii], bv[jj], acc[ii][jj]);
        }
        __syncthreads();
    }
    float4 dv = *(const float4*)&Dv[n0 + (tx << 2)];
    #pragma unroll
    for (int ii = 0; ii < 4; ++ii) {
        int row = m0 + (ty << 2) + ii;
        float4 uv = *(const float4*)&U[(size_t)row * 256 + n0 + (tx << 2)];
        float4 o;
        o.x = acc[ii][0] + dv.x * uv.x;
        o.y = acc[ii][1] + dv.y * uv.y;
        o.z = acc[ii][2] + dv.z * uv.z;
        o.w = acc[ii][3] + dv.w * uv.w;
        *(float4*)&Out[(size_t)row * 256 + n0 + (tx << 2)] = o;
    }
}

// ---------------------------------------------------------------------------
extern "C" void kernel_launch(void* const* d_in, const int* in_sizes, int n_in,
                              void* d_out, int out_size, void* d_ws, size_t ws_size,
                              hipStream_t stream)
{
    const float* u        = (const float*)d_in[0];
    // d_in[1] = prev_state: provably never affects xs (and is zero)
    const float* Lambda   = (const float*)d_in[2];
    const float* B        = (const float*)d_in[3];
    const float* C        = (const float*)d_in[4];
    const float* D        = (const float*)d_in[5];
    const float* log_step = (const float*)d_in[6];
    float* out = (float*)d_out;

    // workspace layout (floats)
    float* Bu        = (float*)d_ws;                         // L*512 = 64 MB
    float* W1        = Bu + (size_t)LSEQ * 512;              // 256*512
    float* W2        = W1 + 256 * 512;                       // 512*256
    float* powt      = W2 + 512 * 256;                       // 65*512
    float* Abar      = powt + (CHUNK + 1) * 512;             // 512
    float* g         = Abar + 512;                           // 512
    float* local_end = g + 512;                              // NCHUNK*512
    float* carry_in  = local_end + (size_t)NCHUNK * 512;     // NCHUNK*512

    s5_prep1<<<1, 256, 0, stream>>>(Lambda, log_step, Abar, g, powt);
    s5_prep2<<<256, 256, 0, stream>>>(B, C, g, W1, W2);
    s5_gemm1<<<dim3(512 / 64, LSEQ / 64), 256, 0, stream>>>(u, W1, Bu);
    s5_scan1<<<NCHUNK, 256, 0, stream>>>(Bu, Abar, local_end);
    s5_scan2<<<1, 256, 0, stream>>>(local_end, carry_in, powt,
                                    out + (size_t)LSEQ * HDIM);
    s5_gemm2<<<dim3(HDIM / 64, LSEQ / 64), 256, 0, stream>>>(Bu, W2, carry_in,
                                                             powt, D, u, out);
}

// Round 2
// 104.190 us; speedup vs baseline: 2.8858x; 2.8858x over previous
//
#include <hip/hip_runtime.h>

#define LSEQ 32768
#define HDIM 256
#define PDIM 256
#define CHUNK 64
#define NCHUNK 512   // LSEQ / CHUNK

typedef __attribute__((ext_vector_type(8))) short short8;
typedef __attribute__((ext_vector_type(4))) float f32x4;

static __device__ __forceinline__ unsigned short f2bf(float f) {
    unsigned int u = __float_as_uint(f);
    return (unsigned short)((u + 0x7FFFu + ((u >> 16) & 1u)) >> 16);
}
static __device__ __forceinline__ float bf2f(unsigned int lo16) {
    return __uint_as_float(lo16 << 16);
}

// ---------------------------------------------------------------------------
// prep1: discretization + power table Abar^k (k=0..CHUNK), fp32
// ---------------------------------------------------------------------------
__global__ void s5_prep1(const float* __restrict__ Lambda,
                         const float* __restrict__ log_step,
                         float* __restrict__ Abar,   // (P,2)
                         float* __restrict__ g,      // (P,2)
                         float* __restrict__ powt)   // (CHUNK+1, 512)
{
    int p = threadIdx.x;
    float lr = Lambda[2 * p], li = Lambda[2 * p + 1];
    float step = expf(log_step[p]);
    float s2 = 0.5f * step;
    float dr = 1.0f - s2 * lr;
    float di = -s2 * li;
    float inv = 1.0f / (dr * dr + di * di);
    float blr = dr * inv, bli = -di * inv;
    float nr = 1.0f + s2 * lr, ni = s2 * li;
    float ar = blr * nr - bli * ni;
    float ai = blr * ni + bli * nr;
    Abar[2 * p] = ar; Abar[2 * p + 1] = ai;
    g[2 * p] = blr * step; g[2 * p + 1] = bli * step;

    float pr = 1.0f, pi = 0.0f;
    powt[2 * p] = 1.0f; powt[2 * p + 1] = 0.0f;
    for (int k = 1; k <= CHUNK; ++k) {
        float t = pr * ar - pi * ai;
        pi = pr * ai + pi * ar;
        pr = t;
        powt[k * 512 + 2 * p] = pr;
        powt[k * 512 + 2 * p + 1] = pi;
    }
}

// ---------------------------------------------------------------------------
// prep2: bf16 transposed weights
//   W1T (2P x H): W1T[2p+ri][h] = (g_p * B~[p][h]) re/im           (N-major)
//   W2T (H x 2P): W2T[h][2p] = C_re[h][p], W2T[h][2p+1] = -C_im    (N-major)
// ---------------------------------------------------------------------------
__global__ void s5_prep2(const float* __restrict__ B,
                         const float* __restrict__ C,
                         const float* __restrict__ g,
                         short* __restrict__ W1T,
                         short* __restrict__ W2T)
{
    int b = blockIdx.x, t = threadIdx.x;
    {   // W1T: p = b, h = t (coalesced along h)
        int p = b, h = t;
        float gr = g[2 * p], gi = g[2 * p + 1];
        float br = B[(size_t)(p * HDIM + h) * 2];
        float bi = B[(size_t)(p * HDIM + h) * 2 + 1];
        W1T[(size_t)(2 * p) * 256 + h]     = (short)f2bf(gr * br - gi * bi);
        W1T[(size_t)(2 * p + 1) * 256 + h] = (short)f2bf(gr * bi + gi * br);
    }
    {   // W2T: h = b, p = t (coalesced along p)
        int h = b, p = t;
        float cr = C[(size_t)(h * PDIM + p) * 2];
        float ci = C[(size_t)(h * PDIM + p) * 2 + 1];
        W2T[(size_t)h * 512 + 2 * p]     = (short)f2bf(cr);
        W2T[(size_t)h * 512 + 2 * p + 1] = (short)f2bf(-ci);
    }
}

// ---------------------------------------------------------------------------
// k1: fused GEMM1 (Bu = u @ W1, bf16 MFMA) + per-chunk local scan.
// Block: chunk c (64 rows) x N-half (256 of 512 cols). 256 thr / 4 waves.
// Emits xs_local (bf16 pairs packed u32) + local_end (fp32).
// ---------------------------------------------------------------------------
__global__ __launch_bounds__(256) void s5_k1(const float* __restrict__ U,
                                             const short* __restrict__ W1T,
                                             const float* __restrict__ Abar,
                                             unsigned int* __restrict__ xs,
                                             float* __restrict__ local_end)
{
    __shared__ char smem[65536];
    short* As = (short*)smem;             // [64][264] bf16 (pad +8)
    short* Bs = (short*)(smem + 33792);   // [256][40] bf16 (pad +8)
    float* sb = (float*)smem;             // [64][256] f32, aliased after GEMM

    const int tid = threadIdx.x;
    const int lane = tid & 63, w = tid >> 6;
    const int n0 = blockIdx.x * 256;
    const int c  = blockIdx.y;
    const int m0 = c * CHUNK;

    // stage full-K A tile: u (64x256 fp32) -> bf16
    #pragma unroll
    for (int i = 0; i < 8; ++i) {
        int gidx = tid + i * 256;
        int row = gidx >> 5, kc = (gidx & 31) << 3;
        const float4* up = (const float4*)&U[(size_t)(m0 + row) * 256 + kc];
        float4 v0 = up[0], v1 = up[1];
        short8 s;
        s[0] = (short)f2bf(v0.x); s[1] = (short)f2bf(v0.y);
        s[2] = (short)f2bf(v0.z); s[3] = (short)f2bf(v0.w);
        s[4] = (short)f2bf(v1.x); s[5] = (short)f2bf(v1.y);
        s[6] = (short)f2bf(v1.z); s[7] = (short)f2bf(v1.w);
        *(short8*)&As[row * 264 + kc] = s;
    }

    f32x4 acc[4][4] = {};

    // stage Bs for k-step 0
    #pragma unroll
    for (int i = 0; i < 4; ++i) {
        int gidx = tid + i * 256;
        int n = gidx >> 2, kc = (gidx & 3) << 3;
        *(short8*)&Bs[n * 40 + kc] = *(const short8*)&W1T[(size_t)(n0 + n) * 256 + kc];
    }

    for (int s = 0; s < 8; ++s) {
        int k0 = s * 32;
        __syncthreads();
        short8 af[4], bfr[4];
        #pragma unroll
        for (int mi = 0; mi < 4; ++mi)
            af[mi] = *(const short8*)&As[(mi * 16 + (lane & 15)) * 264 + k0 + ((lane >> 4) << 3)];
        #pragma unroll
        for (int ni = 0; ni < 4; ++ni)
            bfr[ni] = *(const short8*)&Bs[(w * 64 + ni * 16 + (lane & 15)) * 40 + ((lane >> 4) << 3)];
        #pragma unroll
        for (int mi = 0; mi < 4; ++mi)
            #pragma unroll
            for (int ni = 0; ni < 4; ++ni)
                acc[mi][ni] = __builtin_amdgcn_mfma_f32_16x16x32_bf16(af[mi], bfr[ni], acc[mi][ni], 0, 0, 0);
        __syncthreads();
        if (s < 7) {
            int k1 = k0 + 32;
            #pragma unroll
            for (int i = 0; i < 4; ++i) {
                int gidx = tid + i * 256;
                int n = gidx >> 2, kc = (gidx & 3) << 3;
                *(short8*)&Bs[n * 40 + kc] = *(const short8*)&W1T[(size_t)(n0 + n) * 256 + k1 + kc];
            }
        }
    }

    // acc -> scan buffer (f32), aliased over As/Bs (safe: barrier above)
    #pragma unroll
    for (int mi = 0; mi < 4; ++mi) {
        int row = mi * 16 + ((lane >> 4) << 2);
        #pragma unroll
        for (int ni = 0; ni < 4; ++ni) {
            int col = w * 64 + ni * 16 + (lane & 15);
            #pragma unroll
            for (int r = 0; r < 4; ++r)
                sb[(row + r) * 256 + col] = acc[mi][ni][r];
        }
    }
    __syncthreads();

    // local scan: 128 threads, one complex channel each
    if (tid < 128) {
        float2 a = ((const float2*)Abar)[(n0 >> 1) + tid];
        float xr = 0.0f, xi = 0.0f;
        unsigned int* xsp = xs + (size_t)m0 * 256 + (n0 >> 1) + tid;
        #pragma unroll 8
        for (int r = 0; r < 64; ++r) {
            float2 bu = *(const float2*)&sb[r * 256 + 2 * tid];
            float nr  = fmaf(a.x, xr, fmaf(-a.y, xi, bu.x));
            float nim = fmaf(a.x, xi, fmaf(a.y, xr, bu.y));
            xr = nr; xi = nim;
            xsp[(size_t)r * 256] = (unsigned int)f2bf(xr) | ((unsigned int)f2bf(xi) << 16);
        }
        ((float2*)local_end)[(size_t)c * 256 + (n0 >> 1) + tid] = make_float2(xr, xi);
    }
}

// ---------------------------------------------------------------------------
// scan2: carry scan over 512 chunks (batched loads to pipeline the chain)
// ---------------------------------------------------------------------------
__global__ void s5_scan2(const float* __restrict__ local_end,
                         float* __restrict__ carry,
                         const float* __restrict__ powt,
                         float* __restrict__ out_state)
{
    int p = threadIdx.x;
    float2 A = ((const float2*)powt)[CHUNK * 256 + p];   // Abar^CHUNK
    float cr = 0.0f, ci = 0.0f;
    for (int cb = 0; cb < NCHUNK; cb += 16) {
        float2 e[16];
        #pragma unroll
        for (int j = 0; j < 16; ++j)
            e[j] = ((const float2*)local_end)[(size_t)(cb + j) * 256 + p];
        #pragma unroll
        for (int j = 0; j < 16; ++j) {
            ((float2*)carry)[(size_t)(cb + j) * 256 + p] = make_float2(cr, ci);
            float nr = fmaf(A.x, cr, fmaf(-A.y, ci, e[j].x));
            float ni = fmaf(A.x, ci, fmaf(A.y, cr, e[j].y));
            cr = nr; ci = ni;
        }
    }
    out_state[2 * p] = cr;
    out_state[2 * p + 1] = ci;
}

// ---------------------------------------------------------------------------
// k2: GEMM2 ys = fix(xs) @ W2 + D*u, bf16 MFMA, fixup in fp32 during staging.
// 128x128 tile, K=512, BK=64, 4 waves (2x2).
// ---------------------------------------------------------------------------
__global__ __launch_bounds__(256) void s5_k2(const unsigned int* __restrict__ xs,
                                             const short* __restrict__ W2T,
                                             const float* __restrict__ carry,
                                             const float* __restrict__ powt,
                                             const float* __restrict__ Dv,
                                             const float* __restrict__ U,
                                             float* __restrict__ Out)
{
    __shared__ char smem[36864];
    short* As = (short*)smem;            // [128][72] bf16 (pad +8)
    short* Bs = (short*)(smem + 18432);  // [128][72]

    const int tid = threadIdx.x, lane = tid & 63, w = tid >> 6;
    const int wr = w >> 1, wc = w & 1;
    const int n0 = blockIdx.x * 128;
    const int m0 = blockIdx.y * 128;
    f32x4 acc[4][4] = {};

    for (int s = 0; s < 8; ++s) {
        int k0 = s * 64;
        // --- stage A with carry fixup (fp32), convert to bf16 ---
        #pragma unroll
        for (int i = 0; i < 4; ++i) {
            int gidx = tid + i * 256;
            int row = gidx >> 3, kc = (gidx & 7) << 3;
            int grow = m0 + row;
            uint4 xv = *(const uint4*)&xs[(size_t)grow * 256 + ((k0 + kc) >> 1)];
            const float4* pwp = (const float4*)&powt[(size_t)((grow & 63) + 1) * 512 + k0 + kc];
            const float4* cvp = (const float4*)&carry[(size_t)(grow >> 6) * 512 + k0 + kc];
            float4 p0 = pwp[0], p1 = pwp[1];
            float4 c0 = cvp[0], c1 = cvp[1];
            float r0 = bf2f(xv.x & 0xffffu), i0 = bf2f(xv.x >> 16);
            float r1 = bf2f(xv.y & 0xffffu), i1 = bf2f(xv.y >> 16);
            float r2 = bf2f(xv.z & 0xffffu), i2 = bf2f(xv.z >> 16);
            float r3 = bf2f(xv.w & 0xffffu), i3 = bf2f(xv.w >> 16);
            r0 += p0.x * c0.x - p0.y * c0.y;  i0 += p0.x * c0.y + p0.y * c0.x;
            r1 += p0.z * c0.z - p0.w * c0.w;  i1 += p0.z * c0.w + p0.w * c0.z;
            r2 += p1.x * c1.x - p1.y * c1.y;  i2 += p1.x * c1.y + p1.y * c1.x;
            r3 += p1.z * c1.z - p1.w * c1.w;  i3 += p1.z * c1.w + p1.w * c1.z;
            short8 sv;
            sv[0] = (short)f2bf(r0); sv[1] = (short)f2bf(i0);
            sv[2] = (short)f2bf(r1); sv[3] = (short)f2bf(i1);
            sv[4] = (short)f2bf(r2); sv[5] = (short)f2bf(i2);
            sv[6] = (short)f2bf(r3); sv[7] = (short)f2bf(i3);
            *(short8*)&As[row * 72 + kc] = sv;
        }
        // --- stage B (plain bf16 copy from W2T) ---
        #pragma unroll
        for (int i = 0; i < 4; ++i) {
            int gidx = tid + i * 256;
            int n = gidx >> 3, kc = (gidx & 7) << 3;
            *(short8*)&Bs[n * 72 + kc] = *(const short8*)&W2T[(size_t)(n0 + n) * 512 + k0 + kc];
        }
        __syncthreads();
        #pragma unroll
        for (int ks = 0; ks < 2; ++ks) {
            short8 af[4], bfr[4];
            #pragma unroll
            for (int mi = 0; mi < 4; ++mi)
                af[mi] = *(const short8*)&As[(wr * 64 + mi * 16 + (lane & 15)) * 72 + ks * 32 + ((lane >> 4) << 3)];
            #pragma unroll
            for (int ni = 0; ni < 4; ++ni)
                bfr[ni] = *(const short8*)&Bs[(wc * 64 + ni * 16 + (lane & 15)) * 72 + ks * 32 + ((lane >> 4) << 3)];
            #pragma unroll
            for (int mi = 0; mi < 4; ++mi)
                #pragma unroll
                for (int ni = 0; ni < 4; ++ni)
                    acc[mi][ni] = __builtin_amdgcn_mfma_f32_16x16x32_bf16(af[mi], bfr[ni], acc[mi][ni], 0, 0, 0);
        }
        __syncthreads();
    }

    // epilogue: + D*u, fp32 out
    #pragma unroll
    for (int ni = 0; ni < 4; ++ni) {
        int col = n0 + wc * 64 + ni * 16 + (lane & 15);
        float d = Dv[col];
        #pragma unroll
        for (int mi = 0; mi < 4; ++mi) {
            int rb = m0 + wr * 64 + mi * 16 + ((lane >> 4) << 2);
            #pragma unroll
            for (int r = 0; r < 4; ++r) {
                int row = rb + r;
                Out[(size_t)row * 256 + col] = acc[mi][ni][r] + d * U[(size_t)row * 256 + col];
            }
        }
    }
}

// ---------------------------------------------------------------------------
extern "C" void kernel_launch(void* const* d_in, const int* in_sizes, int n_in,
                              void* d_out, int out_size, void* d_ws, size_t ws_size,
                              hipStream_t stream)
{
    const float* u        = (const float*)d_in[0];
    // d_in[1] = prev_state: provably never affects outputs (see round-0 note)
    const float* Lambda   = (const float*)d_in[2];
    const float* B        = (const float*)d_in[3];
    const float* C        = (const float*)d_in[4];
    const float* D        = (const float*)d_in[5];
    const float* log_step = (const float*)d_in[6];
    float* out = (float*)d_out;

    // workspace layout
    unsigned int* xs = (unsigned int*)d_ws;              // L*256 u32 (bf16 pairs) = 32 MB
    float* powt      = (float*)(xs + (size_t)LSEQ * 256);// 65*512
    float* Abar      = powt + 65 * 512;                  // 512
    float* g         = Abar + 512;                       // 512
    float* local_end = g + 512;                          // 512*512
    float* carry     = local_end + (size_t)NCHUNK * 512; // 512*512
    short* W1T       = (short*)(carry + (size_t)NCHUNK * 512); // 512*256
    short* W2T       = W1T + 512 * 256;                  // 256*512

    s5_prep1<<<1, 256, 0, stream>>>(Lambda, log_step, Abar, g, powt);
    s5_prep2<<<256, 256, 0, stream>>>(B, C, g, W1T, W2T);
    s5_k1<<<dim3(2, NCHUNK), 256, 0, stream>>>(u, W1T, Abar, xs, local_end);
    s5_scan2<<<1, 256, 0, stream>>>(local_end, carry, powt, out + (size_t)LSEQ * HDIM);
    s5_k2<<<dim3(2, 256), 256, 0, stream>>>(xs, W2T, carry, powt, D, u, out);
}